// Round 4
// baseline (1106.326 us; speedup 1.0000x reference)
//
#include <hip/hip_runtime.h>

#define B_ 8
#define N_ 262144
#define M_ 100
#define C_ 7
#define EPSF 1e-7f

__device__ __forceinline__ float softplus0(float x) {
  // jnp.logaddexp(0, x) = max(x,0) + log1p(exp(-|x|))
  return fmaxf(x, 0.0f) + log1pf(expf(-fabsf(x)));
}

// ---------------- fused big kernel ----------------
// grid (N/1024, B), 256 threads. Per block:
//  - softplus partial sum over this chunk's pred_cls (1024 anchors * 7)
//  - for its 1024 anchors: d2 to all 100 GTs (staged in LDS), giving
//      * per-anchor min dist -> neg weight partial sum
//      * per-GT argmin candidate -> LDS-filtered atomicMin -> global atomicMin
__global__ void k_fused(const float* __restrict__ pred_cls,
                        const float* __restrict__ anchors,
                        const float* __restrict__ gt_boxes,
                        unsigned long long* __restrict__ amin,
                        double* __restrict__ sp_sum,
                        double* __restrict__ swb_sum) {
  const int b = blockIdx.y;
  const int c = blockIdx.x;   // anchor chunk (1024 anchors)
  const int t = threadIdx.x;  // 256

  __shared__ float4 gt4[M_];               // (gx, gy, gx^2+gy^2, -)
  __shared__ unsigned long long best[M_];  // packed (d2bits<<32)|n
  __shared__ float red[256];

  if (t < M_) {
    float4 g = reinterpret_cast<const float4*>(gt_boxes)[b * M_ + t];
    float gx = __fmul_rn(__fadd_rn(g.x, g.z), 0.5f);
    float gy = __fmul_rn(__fadd_rn(g.y, g.w), 0.5f);
    gt4[t] = make_float4(gx, gy, __fadd_rn(__fmul_rn(gx, gx), __fmul_rn(gy, gy)), 0.f);
    best[t] = 0xffffffffffffffffULL;
  }

  // softplus over this block's slice: 7168 floats = 1792 float4
  const float4* pc = reinterpret_cast<const float4*>(
      pred_cls + (size_t)b * (size_t)(N_ * C_) + (size_t)c * (1024 * C_));
  float acc_sp = 0.f;
#pragma unroll
  for (int k = 0; k < 7; ++k) {
    float4 v = pc[t + k * 256];
    acc_sp += softplus0(v.x) + softplus0(v.y) + softplus0(v.z) + softplus0(v.w);
  }

  // 4 anchors per thread, strided for coalescing
  const int n0 = c * 1024;
  float ax[4], ay[4], t2[4], mind[4];
#pragma unroll
  for (int k = 0; k < 4; ++k) {
    float2 a = reinterpret_cast<const float2*>(anchors)[n0 + t + k * 256];
    ax[k] = a.x; ay[k] = a.y;
    t2[k] = __fadd_rn(__fmul_rn(a.x, a.x), __fmul_rn(a.y, a.y));
    mind[k] = __int_as_float(0x7f800000);
  }
  __syncthreads();

#pragma unroll 2
  for (int m = 0; m < M_; ++m) {
    const float4 g = gt4[m];
    float bd = __int_as_float(0x7f800000);
    unsigned bn = 0;
#pragma unroll
    for (int k = 0; k < 4; ++k) {
      float dot = __fmaf_rn(g.y, ay[k], __fmul_rn(g.x, ax[k]));
      float d2  = __fsub_rn(__fadd_rn(g.z, t2[k]), __fadd_rn(dot, dot));
      d2 = fmaxf(d2, 0.0f);               // ref: sqrt(clip(d2,0))
      mind[k] = fminf(mind[k], d2);
      if (d2 < bd) { bd = d2; bn = (unsigned)(n0 + t + k * 256); }  // strict < => lowest n
    }
    unsigned long long pk =
        ((unsigned long long)__float_as_uint(bd) << 32) | (unsigned long long)bn;
    if (pk < best[m]) atomicMin(&best[m], pk);  // stale read is only a filter
  }

  float accw = 0.f;
#pragma unroll
  for (int k = 0; k < 4; ++k) accw += (sqrtf(mind[k]) > 3.0f) ? 1.0f : 0.1f;

  // reductions: softplus, then neg-weight base; then per-m global atomicMin
  red[t] = acc_sp;
  __syncthreads();
  for (int s = 128; s > 0; s >>= 1) {
    if (t < s) red[t] += red[t + s];
    __syncthreads();
  }
  if (t == 0) atomicAdd(&sp_sum[b], (double)red[0]);
  __syncthreads();
  red[t] = accw;
  __syncthreads();
  for (int s = 128; s > 0; s >>= 1) {
    if (t < s) red[t] += red[t + s];
    __syncthreads();
  }
  if (t == 0) atomicAdd(&swb_sum[b], (double)red[0]);
  if (t < M_) atomicMin(&amin[b * M_ + t], best[t]);
}

// ---------------- per-image finalize ----------------
__global__ void k_final_img(const float* __restrict__ pred_cls,
                            const float* __restrict__ pred_reg,
                            const float* __restrict__ anchors,
                            const float* __restrict__ strides,
                            const float* __restrict__ gt_boxes,
                            const int* __restrict__ gt_labels,
                            const unsigned long long* __restrict__ amin,
                            const double* __restrict__ sp_sum,
                            const double* __restrict__ swb_sum,
                            float* __restrict__ lc, float* __restrict__ lb) {
  const int b = blockIdx.x;
  const int t = threadIdx.x;  // 128
  __shared__ unsigned asg[M_];
  __shared__ int cid[M_];
  __shared__ unsigned srt[M_];
  __shared__ float4 gt4[M_];
  __shared__ float red[128];
  __shared__ int dupCount;
  if (t == 0) dupCount = 0;
  if (t < M_) {
    asg[t] = (unsigned)(amin[b * M_ + t] & 0xffffffffULL);
    int c = gt_labels[b * M_ + t] - 1;
    c = c < 0 ? 0 : (c > C_ - 1 ? C_ - 1 : c);
    cid[t] = c;
    float4 g = reinterpret_cast<const float4*>(gt_boxes)[b * M_ + t];
    float gx = __fmul_rn(__fadd_rn(g.x, g.z), 0.5f);
    float gy = __fmul_rn(__fadd_rn(g.y, g.w), 0.5f);
    gt4[t] = make_float4(gx, gy, __fadd_rn(__fmul_rn(gx, gx), __fmul_rn(gy, gy)), 0.f);
  }
  __syncthreads();

  // tgt sum with (anchor,cls)-pair dedup; anchor-dup detection for uniqueness;
  // pos-correction: for each DISTINCT assigned anchor add its neg-weight.
  float tg = 0.f, corr = 0.f;
  if (t < M_) {
    bool dupPair = false, dupIdx = false;
    for (int m = 0; m < t; ++m) {
      if (asg[m] == asg[t]) {
        dupIdx = true;
        if (cid[m] == cid[t]) dupPair = true;
      }
    }
    if (!dupPair) tg = pred_cls[((size_t)b * N_ + asg[t]) * C_ + cid[t]];
    if (dupIdx) atomicAdd(&dupCount, 1);
    if (!dupIdx) {
      float2 a = reinterpret_cast<const float2*>(anchors)[asg[t]];
      float t2 = __fadd_rn(__fmul_rn(a.x, a.x), __fmul_rn(a.y, a.y));
      float mind = __int_as_float(0x7f800000);
      for (int m = 0; m < M_; ++m) {
        float4 g = gt4[m];
        float dot = __fmaf_rn(g.y, a.y, __fmul_rn(g.x, a.x));
        float d2  = __fsub_rn(__fadd_rn(g.z, t2), __fadd_rn(dot, dot));
        mind = fminf(mind, fmaxf(d2, 0.0f));
      }
      corr = (sqrtf(mind) > 3.0f) ? 1.0f : 0.1f;
    }
  }
  red[t] = tg;
  __syncthreads();
  for (int s = 64; s > 0; s >>= 1) {
    if (t < s) red[t] += red[t + s];
    __syncthreads();
  }
  const float tgt_total = red[0];
  __syncthreads();
  red[t] = corr;
  __syncthreads();
  for (int s = 64; s > 0; s >>= 1) {
    if (t < s) red[t] += red[t + s];
    __syncthreads();
  }
  const float corr_total = red[0];
  const bool uniqueAll = (dupCount == 0);
  __syncthreads();

  if (uniqueAll && t < M_) {
    const unsigned v = asg[t];
    int rank = 0;
    for (int m = 0; m < M_; ++m) rank += (asg[m] < v) ? 1 : 0;
    srt[rank] = v;
  }
  __syncthreads();

  float gl = 0.f;
  if (t < M_) {
    const unsigned q = uniqueAll ? srt[t] : asg[t];
    float4 r = reinterpret_cast<const float4*>(pred_reg)[(size_t)b * N_ + q];
    float2 a = reinterpret_cast<const float2*>(anchors)[q];
    float s = strides[q];
    float cx = a.x + r.x * s, cy = a.y + r.y * s;
    float hx = (expf(r.z) * s) * 0.5f, hy = (expf(r.w) * s) * 0.5f;
    float px0 = cx - hx, py0 = cy - hy, px1 = cx + hx, py1 = cy + hy;
    float4 g = reinterpret_cast<const float4*>(gt_boxes)[b * M_ + t];
    float ap = (px1 - px0) * (py1 - py0);
    float ag = (g.z - g.x) * (g.w - g.y);
    float ltx = fmaxf(px0, g.x), lty = fmaxf(py0, g.y);
    float rbx = fminf(px1, g.z), rby = fminf(py1, g.w);
    float wix = fmaxf(rbx - ltx, 0.f), wiy = fmaxf(rby - lty, 0.f);
    float inter = wix * wiy;
    float uni = ap + ag - inter;
    float iou = inter / (uni + EPSF);
    float lcx = fminf(px0, g.x), lcy = fminf(py0, g.y);
    float rcx = fmaxf(px1, g.z), rcy = fmaxf(py1, g.w);
    float wcx = fmaxf(rcx - lcx, 0.f), wcy = fmaxf(rcy - lcy, 0.f);
    float ac = wcx * wcy;
    float giou = iou - (ac - uni) / (ac + EPSF);
    gl = 1.f - giou;
  }
  __syncthreads();
  red[t] = gl;
  __syncthreads();
  for (int s = 64; s > 0; s >>= 1) {
    if (t < s) red[t] += red[t + s];
    __syncthreads();
  }
  if (t == 0) {
    lb[b] = red[0] / (float)M_;
    float bce = (float)((sp_sum[b] - (double)tgt_total) / (double)(N_ * C_));
    float swm = (float)((swb_sum[b] + (double)corr_total) / (double)N_);
    lc[b] = bce * swm;
  }
}

// ---------------- scalar combine ----------------
__global__ void k_total(const float* __restrict__ lc, const float* __restrict__ lb,
                        float* __restrict__ out) {
  if (threadIdx.x == 0 && blockIdx.x == 0) {
    float sc = 0.f, sb = 0.f;
    for (int b = 0; b < B_; ++b) { sc += lc[b]; sb += lb[b]; }
    out[0] = sc / 8.0f + 2.0f * (sb / 8.0f);
  }
}

// ---------------- launch ----------------
extern "C" void kernel_launch(void* const* d_in, const int* in_sizes, int n_in,
                              void* d_out, int out_size, void* d_ws, size_t ws_size,
                              hipStream_t stream) {
  (void)in_sizes; (void)n_in; (void)out_size; (void)ws_size;
  const float* pred_cls  = (const float*)d_in[0];
  const float* pred_reg  = (const float*)d_in[1];
  const float* anchors   = (const float*)d_in[2];
  const float* strides   = (const float*)d_in[3];
  const float* gt_boxes  = (const float*)d_in[4];
  const int*   gt_labels = (const int*)d_in[5];
  float* out = (float*)d_out;

  char* ws = (char*)d_ws;
  double* sp_sum  = (double*)(ws);                       // 8 doubles
  double* swb_sum = (double*)(ws + 64);                  // 8 doubles
  unsigned long long* amin = (unsigned long long*)(ws + 128);  // 800 u64
  float* lc = (float*)(ws + 128 + 6400);                 // 8 floats
  float* lb = (float*)(ws + 128 + 6400 + 32);            // 8 floats

  hipMemsetAsync(ws, 0, 128, stream);          // zero accumulators
  hipMemsetAsync(ws + 128, 0xFF, 6400, stream);  // amin = +inf pack

  k_fused<<<dim3(N_ / 1024, B_), dim3(256), 0, stream>>>(pred_cls, anchors, gt_boxes,
                                                         amin, sp_sum, swb_sum);
  k_final_img<<<dim3(B_), dim3(128), 0, stream>>>(pred_cls, pred_reg, anchors, strides,
                                                  gt_boxes, gt_labels, amin, sp_sum,
                                                  swb_sum, lc, lb);
  k_total<<<dim3(1), dim3(64), 0, stream>>>(lc, lb, out);
}

// Round 5
// 387.349 us; speedup vs baseline: 2.8561x; 2.8561x over previous
//
#include <hip/hip_runtime.h>

#define B_ 8
#define N_ 262144
#define M_ 100
#define C_ 7
#define EPSF 1e-7f
#define SEG_ 4                      // anchor-scan segments per (b,m) in k_argmin
#define SEGN_ (N_ / SEG_)           // 65536 anchors per segment

__device__ __forceinline__ float softplus0(float x) {
  // jnp.logaddexp(0, x) = max(x,0) + log1p(exp(-|x|))
  return fmaxf(x, 0.0f) + log1pf(expf(-fabsf(x)));
}

// ---------------- K_A: softplus sum + per-anchor neg-weight sum ----------------
// grid (N/1024, B), 256 threads. NO argmin machinery, NO contended atomics:
// just two f64 atomicAdds per block (proven harmless in R0).
__global__ void k_passA(const float* __restrict__ pred_cls,
                        const float* __restrict__ anchors,
                        const float* __restrict__ gt_boxes,
                        double* __restrict__ sp_sum,
                        double* __restrict__ swb_sum) {
  const int b = blockIdx.y;
  const int c = blockIdx.x;   // anchor chunk (1024 anchors)
  const int t = threadIdx.x;  // 256

  __shared__ float4 gt4[M_];  // (gx, gy, gx^2+gy^2, -)
  __shared__ float red[256];

  if (t < M_) {
    float4 g = reinterpret_cast<const float4*>(gt_boxes)[b * M_ + t];
    float gx = __fmul_rn(__fadd_rn(g.x, g.z), 0.5f);
    float gy = __fmul_rn(__fadd_rn(g.y, g.w), 0.5f);
    gt4[t] = make_float4(gx, gy, __fadd_rn(__fmul_rn(gx, gx), __fmul_rn(gy, gy)), 0.f);
  }

  // softplus over this block's slice: 7168 floats = 1792 float4
  const float4* pc = reinterpret_cast<const float4*>(
      pred_cls + (size_t)b * (size_t)(N_ * C_) + (size_t)c * (1024 * C_));
  float acc_sp = 0.f;
#pragma unroll
  for (int k = 0; k < 7; ++k) {
    float4 v = pc[t + k * 256];
    acc_sp += softplus0(v.x) + softplus0(v.y) + softplus0(v.z) + softplus0(v.w);
  }

  // 4 anchors per thread, strided for coalescing
  const int n0 = c * 1024;
  float ax[4], ay[4], t2[4], mind[4];
#pragma unroll
  for (int k = 0; k < 4; ++k) {
    float2 a = reinterpret_cast<const float2*>(anchors)[n0 + t + k * 256];
    ax[k] = a.x; ay[k] = a.y;
    t2[k] = __fadd_rn(__fmul_rn(a.x, a.x), __fmul_rn(a.y, a.y));
    mind[k] = __int_as_float(0x7f800000);
  }
  __syncthreads();

#pragma unroll 2
  for (int m = 0; m < M_; ++m) {
    const float4 g = gt4[m];
#pragma unroll
    for (int k = 0; k < 4; ++k) {
      float dot = __fmaf_rn(g.y, ay[k], __fmul_rn(g.x, ax[k]));
      float d2  = __fsub_rn(__fadd_rn(g.z, t2[k]), __fadd_rn(dot, dot));
      mind[k] = fminf(mind[k], fmaxf(d2, 0.0f));  // ref: sqrt(clip(d2,0))
    }
  }

  float accw = 0.f;
#pragma unroll
  for (int k = 0; k < 4; ++k) accw += (sqrtf(mind[k]) > 3.0f) ? 1.0f : 0.1f;

  red[t] = acc_sp;
  __syncthreads();
  for (int s = 128; s > 0; s >>= 1) {
    if (t < s) red[t] += red[t + s];
    __syncthreads();
  }
  if (t == 0) atomicAdd(&sp_sum[b], (double)red[0]);
  __syncthreads();
  red[t] = accw;
  __syncthreads();
  for (int s = 128; s > 0; s >>= 1) {
    if (t < s) red[t] += red[t + s];
    __syncthreads();
  }
  if (t == 0) atomicAdd(&swb_sum[b], (double)red[0]);
}

// ---------------- K_B: argmin_n dist(gt, anchor), split-N for occupancy ----------------
// grid (SEG_, B*M), 256 threads. R0's verified kernel + 4-way anchor split;
// per-block LDS u64 tree then ONE global atomicMin (4 contenders/address).
__global__ void k_argmin(const float* __restrict__ anchors,
                         const float* __restrict__ gt_boxes,
                         unsigned long long* __restrict__ amin) {
  const int bm  = blockIdx.y;
  const int seg = blockIdx.x;
  const float4 g = reinterpret_cast<const float4*>(gt_boxes)[bm];
  const float gx = __fmul_rn(__fadd_rn(g.x, g.z), 0.5f);
  const float gy = __fmul_rn(__fadd_rn(g.y, g.w), 0.5f);
  const float t1 = __fadd_rn(__fmul_rn(gx, gx), __fmul_rn(gy, gy));
  const float2* an = reinterpret_cast<const float2*>(anchors);
  float best = __int_as_float(0x7f800000);  // +inf
  unsigned bestn = 0;
  const int n0 = seg * SEGN_;
#pragma unroll 4
  for (int n = n0 + threadIdx.x; n < n0 + SEGN_; n += 256) {
    float2 a = an[n];
    float t2  = __fadd_rn(__fmul_rn(a.x, a.x), __fmul_rn(a.y, a.y));
    float dot = __fmaf_rn(gy, a.y, __fmul_rn(gx, a.x));
    float d2  = __fsub_rn(__fadd_rn(t1, t2), __fadd_rn(dot, dot));
    d2 = fmaxf(d2, 0.0f);  // ref: sqrt(clip(d2,0)); ties at 0 -> first idx
    if (d2 < best) { best = d2; bestn = (unsigned)n; }  // strict < keeps earliest n
  }
  unsigned long long pk =
      ((unsigned long long)__float_as_uint(best) << 32) | (unsigned long long)bestn;
  __shared__ unsigned long long red[256];
  const int t = threadIdx.x;
  red[t] = pk;
  __syncthreads();
  for (int s = 128; s > 0; s >>= 1) {
    if (t < s) {
      unsigned long long o = red[t + s];
      if (o < red[t]) red[t] = o;
    }
    __syncthreads();
  }
  if (t == 0) atomicMin(&amin[bm], red[0]);
}

// ---------------- per-image finalize ----------------
__global__ void k_final_img(const float* __restrict__ pred_cls,
                            const float* __restrict__ pred_reg,
                            const float* __restrict__ anchors,
                            const float* __restrict__ strides,
                            const float* __restrict__ gt_boxes,
                            const int* __restrict__ gt_labels,
                            const unsigned long long* __restrict__ amin,
                            const double* __restrict__ sp_sum,
                            const double* __restrict__ swb_sum,
                            float* __restrict__ lc, float* __restrict__ lb) {
  const int b = blockIdx.x;
  const int t = threadIdx.x;  // 128
  __shared__ unsigned asg[M_];
  __shared__ int cid[M_];
  __shared__ unsigned srt[M_];
  __shared__ float4 gt4[M_];
  __shared__ float red[128];
  __shared__ int dupCount;
  if (t == 0) dupCount = 0;
  if (t < M_) {
    asg[t] = (unsigned)(amin[b * M_ + t] & 0xffffffffULL);
    int c = gt_labels[b * M_ + t] - 1;
    c = c < 0 ? 0 : (c > C_ - 1 ? C_ - 1 : c);
    cid[t] = c;
    float4 g = reinterpret_cast<const float4*>(gt_boxes)[b * M_ + t];
    float gx = __fmul_rn(__fadd_rn(g.x, g.z), 0.5f);
    float gy = __fmul_rn(__fadd_rn(g.y, g.w), 0.5f);
    gt4[t] = make_float4(gx, gy, __fadd_rn(__fmul_rn(gx, gx), __fmul_rn(gy, gy)), 0.f);
  }
  __syncthreads();

  // tgt sum with (anchor,cls)-pair dedup; anchor-dup detection for uniqueness;
  // pos-correction: for each DISTINCT assigned anchor add its neg-weight.
  float tg = 0.f, corr = 0.f;
  if (t < M_) {
    bool dupPair = false, dupIdx = false;
    for (int m = 0; m < t; ++m) {
      if (asg[m] == asg[t]) {
        dupIdx = true;
        if (cid[m] == cid[t]) dupPair = true;
      }
    }
    if (!dupPair) tg = pred_cls[((size_t)b * N_ + asg[t]) * C_ + cid[t]];
    if (dupIdx) atomicAdd(&dupCount, 1);
    if (!dupIdx) {
      float2 a = reinterpret_cast<const float2*>(anchors)[asg[t]];
      float t2 = __fadd_rn(__fmul_rn(a.x, a.x), __fmul_rn(a.y, a.y));
      float mind = __int_as_float(0x7f800000);
      for (int m = 0; m < M_; ++m) {
        float4 g = gt4[m];
        float dot = __fmaf_rn(g.y, a.y, __fmul_rn(g.x, a.x));
        float d2  = __fsub_rn(__fadd_rn(g.z, t2), __fadd_rn(dot, dot));
        mind = fminf(mind, fmaxf(d2, 0.0f));
      }
      corr = (sqrtf(mind) > 3.0f) ? 1.0f : 0.1f;
    }
  }
  red[t] = tg;
  __syncthreads();
  for (int s = 64; s > 0; s >>= 1) {
    if (t < s) red[t] += red[t + s];
    __syncthreads();
  }
  const float tgt_total = red[0];
  __syncthreads();
  red[t] = corr;
  __syncthreads();
  for (int s = 64; s > 0; s >>= 1) {
    if (t < s) red[t] += red[t + s];
    __syncthreads();
  }
  const float corr_total = red[0];
  const bool uniqueAll = (dupCount == 0);
  __syncthreads();

  if (uniqueAll && t < M_) {
    const unsigned v = asg[t];
    int rank = 0;
    for (int m = 0; m < M_; ++m) rank += (asg[m] < v) ? 1 : 0;
    srt[rank] = v;
  }
  __syncthreads();

  float gl = 0.f;
  if (t < M_) {
    const unsigned q = uniqueAll ? srt[t] : asg[t];
    float4 r = reinterpret_cast<const float4*>(pred_reg)[(size_t)b * N_ + q];
    float2 a = reinterpret_cast<const float2*>(anchors)[q];
    float s = strides[q];
    float cx = a.x + r.x * s, cy = a.y + r.y * s;
    float hx = (expf(r.z) * s) * 0.5f, hy = (expf(r.w) * s) * 0.5f;
    float px0 = cx - hx, py0 = cy - hy, px1 = cx + hx, py1 = cy + hy;
    float4 g = reinterpret_cast<const float4*>(gt_boxes)[b * M_ + t];
    float ap = (px1 - px0) * (py1 - py0);
    float ag = (g.z - g.x) * (g.w - g.y);
    float ltx = fmaxf(px0, g.x), lty = fmaxf(py0, g.y);
    float rbx = fminf(px1, g.z), rby = fminf(py1, g.w);
    float wix = fmaxf(rbx - ltx, 0.f), wiy = fmaxf(rby - lty, 0.f);
    float inter = wix * wiy;
    float uni = ap + ag - inter;
    float iou = inter / (uni + EPSF);
    float lcx = fminf(px0, g.x), lcy = fminf(py0, g.y);
    float rcx = fmaxf(px1, g.z), rcy = fmaxf(py1, g.w);
    float wcx = fmaxf(rcx - lcx, 0.f), wcy = fmaxf(rcy - lcy, 0.f);
    float ac = wcx * wcy;
    float giou = iou - (ac - uni) / (ac + EPSF);
    gl = 1.f - giou;
  }
  __syncthreads();
  red[t] = gl;
  __syncthreads();
  for (int s = 64; s > 0; s >>= 1) {
    if (t < s) red[t] += red[t + s];
    __syncthreads();
  }
  if (t == 0) {
    lb[b] = red[0] / (float)M_;
    float bce = (float)((sp_sum[b] - (double)tgt_total) / (double)(N_ * C_));
    float swm = (float)((swb_sum[b] + (double)corr_total) / (double)N_);
    lc[b] = bce * swm;
  }
}

// ---------------- scalar combine ----------------
__global__ void k_total(const float* __restrict__ lc, const float* __restrict__ lb,
                        float* __restrict__ out) {
  if (threadIdx.x == 0 && blockIdx.x == 0) {
    float sc = 0.f, sb = 0.f;
    for (int b = 0; b < B_; ++b) { sc += lc[b]; sb += lb[b]; }
    out[0] = sc / 8.0f + 2.0f * (sb / 8.0f);
  }
}

// ---------------- launch ----------------
extern "C" void kernel_launch(void* const* d_in, const int* in_sizes, int n_in,
                              void* d_out, int out_size, void* d_ws, size_t ws_size,
                              hipStream_t stream) {
  (void)in_sizes; (void)n_in; (void)out_size; (void)ws_size;
  const float* pred_cls  = (const float*)d_in[0];
  const float* pred_reg  = (const float*)d_in[1];
  const float* anchors   = (const float*)d_in[2];
  const float* strides   = (const float*)d_in[3];
  const float* gt_boxes  = (const float*)d_in[4];
  const int*   gt_labels = (const int*)d_in[5];
  float* out = (float*)d_out;

  char* ws = (char*)d_ws;
  double* sp_sum  = (double*)(ws);                       // 8 doubles
  double* swb_sum = (double*)(ws + 64);                  // 8 doubles
  unsigned long long* amin = (unsigned long long*)(ws + 128);  // 800 u64
  float* lc = (float*)(ws + 128 + 6400);                 // 8 floats
  float* lb = (float*)(ws + 128 + 6400 + 32);            // 8 floats

  hipMemsetAsync(ws, 0, 128, stream);            // zero accumulators
  hipMemsetAsync(ws + 128, 0xFF, 6400, stream);  // amin = +inf pack

  k_passA<<<dim3(N_ / 1024, B_), dim3(256), 0, stream>>>(pred_cls, anchors, gt_boxes,
                                                         sp_sum, swb_sum);
  k_argmin<<<dim3(SEG_, B_ * M_), dim3(256), 0, stream>>>(anchors, gt_boxes, amin);
  k_final_img<<<dim3(B_), dim3(128), 0, stream>>>(pred_cls, pred_reg, anchors, strides,
                                                  gt_boxes, gt_labels, amin, sp_sum,
                                                  swb_sum, lc, lb);
  k_total<<<dim3(1), dim3(64), 0, stream>>>(lc, lb, out);
}

// Round 6
// 302.578 us; speedup vs baseline: 3.6563x; 1.2802x over previous
//
#include <hip/hip_runtime.h>

#define B_ 8
#define N_ 262144
#define M_ 100
#define C_ 7
#define EPSF 1e-7f
#define SEG_ 4                      // anchor-scan segments per (b,m) in k_argmin
#define SEGN_ (N_ / SEG_)           // 65536 anchors per segment

__device__ __forceinline__ float softplus0(float x) {
  // jnp.logaddexp(0, x) = max(x,0) + log1p(exp(-|x|))
  return fmaxf(x, 0.0f) + log1pf(expf(-fabsf(x)));
}

// ---------------- K_A: softplus sum + per-anchor neg-weight sum ----------------
// grid (N/1024, B), 256 threads. Two sequential phases so live ranges don't
// overlap (R5 post-mortem: VGPR=64 cap + spill => 276 MB scratch writes).
__global__ void __launch_bounds__(256)
k_passA(const float* __restrict__ pred_cls,
        const float* __restrict__ anchors,
        const float* __restrict__ gt_boxes,
        double* __restrict__ sp_sum,
        double* __restrict__ swb_sum) {
  const int b = blockIdx.y;
  const int c = blockIdx.x;   // anchor chunk (1024 anchors)
  const int t = threadIdx.x;  // 256

  __shared__ float4 gt4[M_];  // (gx, gy, gx^2+gy^2, -)
  __shared__ float red[256];

  if (t < M_) {
    float4 g = reinterpret_cast<const float4*>(gt_boxes)[b * M_ + t];
    float gx = __fmul_rn(__fadd_rn(g.x, g.z), 0.5f);
    float gy = __fmul_rn(__fadd_rn(g.y, g.w), 0.5f);
    gt4[t] = make_float4(gx, gy, __fadd_rn(__fmul_rn(gx, gx), __fmul_rn(gy, gy)), 0.f);
  }

  // ---- phase 1: softplus over this block's slice (1792 float4), fully
  // reduced and retired before any anchor state is live.
  const float4* pc = reinterpret_cast<const float4*>(
      pred_cls + (size_t)b * (size_t)(N_ * C_) + (size_t)c * (1024 * C_));
  float acc_sp = 0.f;
#pragma unroll
  for (int k = 0; k < 7; ++k) {
    float4 v = pc[t + k * 256];
    acc_sp += softplus0(v.x) + softplus0(v.y) + softplus0(v.z) + softplus0(v.w);
  }
  red[t] = acc_sp;
  __syncthreads();
  for (int s = 128; s > 0; s >>= 1) {
    if (t < s) red[t] += red[t + s];
    __syncthreads();
  }
  if (t == 0) atomicAdd(&sp_sum[b], (double)red[0]);

  // ---- phase 2: 4 anchors per thread, min dist over 100 GTs (LDS).
  const int n0 = c * 1024;
  float ax[4], ay[4], t2[4], mind[4];
#pragma unroll
  for (int k = 0; k < 4; ++k) {
    float2 a = reinterpret_cast<const float2*>(anchors)[n0 + t + k * 256];
    ax[k] = a.x; ay[k] = a.y;
    t2[k] = __fadd_rn(__fmul_rn(a.x, a.x), __fmul_rn(a.y, a.y));
    mind[k] = __int_as_float(0x7f800000);
  }

#pragma unroll 2
  for (int m = 0; m < M_; ++m) {
    const float4 g = gt4[m];
#pragma unroll
    for (int k = 0; k < 4; ++k) {
      float dot = __fmaf_rn(g.y, ay[k], __fmul_rn(g.x, ax[k]));
      float d2  = __fsub_rn(__fadd_rn(g.z, t2[k]), __fadd_rn(dot, dot));
      mind[k] = fminf(mind[k], fmaxf(d2, 0.0f));  // ref: sqrt(clip(d2,0))
    }
  }

  float accw = 0.f;
#pragma unroll
  for (int k = 0; k < 4; ++k) accw += (sqrtf(mind[k]) > 3.0f) ? 1.0f : 0.1f;

  __syncthreads();
  red[t] = accw;
  __syncthreads();
  for (int s = 128; s > 0; s >>= 1) {
    if (t < s) red[t] += red[t + s];
    __syncthreads();
  }
  if (t == 0) atomicAdd(&swb_sum[b], (double)red[0]);
}

// ---------------- K_B: argmin_n dist(gt, anchor), split-N for occupancy ----------------
// grid (SEG_, B*M), 256 threads. Per-block LDS u64 tree then ONE global
// atomicMin (4 contenders/address).
__global__ void __launch_bounds__(256)
k_argmin(const float* __restrict__ anchors,
         const float* __restrict__ gt_boxes,
         unsigned long long* __restrict__ amin) {
  const int bm  = blockIdx.y;
  const int seg = blockIdx.x;
  const float4 g = reinterpret_cast<const float4*>(gt_boxes)[bm];
  const float gx = __fmul_rn(__fadd_rn(g.x, g.z), 0.5f);
  const float gy = __fmul_rn(__fadd_rn(g.y, g.w), 0.5f);
  const float t1 = __fadd_rn(__fmul_rn(gx, gx), __fmul_rn(gy, gy));
  const float2* an = reinterpret_cast<const float2*>(anchors);
  float best = __int_as_float(0x7f800000);  // +inf
  unsigned bestn = 0;
  const int n0 = seg * SEGN_;
#pragma unroll 4
  for (int n = n0 + threadIdx.x; n < n0 + SEGN_; n += 256) {
    float2 a = an[n];
    float t2  = __fadd_rn(__fmul_rn(a.x, a.x), __fmul_rn(a.y, a.y));
    float dot = __fmaf_rn(gy, a.y, __fmul_rn(gx, a.x));
    float d2  = __fsub_rn(__fadd_rn(t1, t2), __fadd_rn(dot, dot));
    d2 = fmaxf(d2, 0.0f);  // ref: sqrt(clip(d2,0)); ties at 0 -> first idx
    if (d2 < best) { best = d2; bestn = (unsigned)n; }  // strict < keeps earliest n
  }
  unsigned long long pk =
      ((unsigned long long)__float_as_uint(best) << 32) | (unsigned long long)bestn;
  __shared__ unsigned long long red[256];
  const int t = threadIdx.x;
  red[t] = pk;
  __syncthreads();
  for (int s = 128; s > 0; s >>= 1) {
    if (t < s) {
      unsigned long long o = red[t + s];
      if (o < red[t]) red[t] = o;
    }
    __syncthreads();
  }
  if (t == 0) atomicMin(&amin[bm], red[0]);
}

// ---------------- per-image finalize ----------------
__global__ void __launch_bounds__(128)
k_final_img(const float* __restrict__ pred_cls,
            const float* __restrict__ pred_reg,
            const float* __restrict__ anchors,
            const float* __restrict__ strides,
            const float* __restrict__ gt_boxes,
            const int* __restrict__ gt_labels,
            const unsigned long long* __restrict__ amin,
            const double* __restrict__ sp_sum,
            const double* __restrict__ swb_sum,
            float* __restrict__ lc, float* __restrict__ lb) {
  const int b = blockIdx.x;
  const int t = threadIdx.x;  // 128
  __shared__ unsigned asg[M_];
  __shared__ int cid[M_];
  __shared__ unsigned srt[M_];
  __shared__ float4 gt4[M_];
  __shared__ float red[128];
  __shared__ int dupCount;
  if (t == 0) dupCount = 0;
  if (t < M_) {
    asg[t] = (unsigned)(amin[b * M_ + t] & 0xffffffffULL);
    int c = gt_labels[b * M_ + t] - 1;
    c = c < 0 ? 0 : (c > C_ - 1 ? C_ - 1 : c);
    cid[t] = c;
    float4 g = reinterpret_cast<const float4*>(gt_boxes)[b * M_ + t];
    float gx = __fmul_rn(__fadd_rn(g.x, g.z), 0.5f);
    float gy = __fmul_rn(__fadd_rn(g.y, g.w), 0.5f);
    gt4[t] = make_float4(gx, gy, __fadd_rn(__fmul_rn(gx, gx), __fmul_rn(gy, gy)), 0.f);
  }
  __syncthreads();

  // tgt sum with (anchor,cls)-pair dedup; anchor-dup detection for uniqueness;
  // pos-correction: for each DISTINCT assigned anchor add its neg-weight.
  float tg = 0.f, corr = 0.f;
  if (t < M_) {
    bool dupPair = false, dupIdx = false;
    for (int m = 0; m < t; ++m) {
      if (asg[m] == asg[t]) {
        dupIdx = true;
        if (cid[m] == cid[t]) dupPair = true;
      }
    }
    if (!dupPair) tg = pred_cls[((size_t)b * N_ + asg[t]) * C_ + cid[t]];
    if (dupIdx) atomicAdd(&dupCount, 1);
    if (!dupIdx) {
      float2 a = reinterpret_cast<const float2*>(anchors)[asg[t]];
      float t2 = __fadd_rn(__fmul_rn(a.x, a.x), __fmul_rn(a.y, a.y));
      float mind = __int_as_float(0x7f800000);
      for (int m = 0; m < M_; ++m) {
        float4 g = gt4[m];
        float dot = __fmaf_rn(g.y, a.y, __fmul_rn(g.x, a.x));
        float d2  = __fsub_rn(__fadd_rn(g.z, t2), __fadd_rn(dot, dot));
        mind = fminf(mind, fmaxf(d2, 0.0f));
      }
      corr = (sqrtf(mind) > 3.0f) ? 1.0f : 0.1f;
    }
  }
  red[t] = tg;
  __syncthreads();
  for (int s = 64; s > 0; s >>= 1) {
    if (t < s) red[t] += red[t + s];
    __syncthreads();
  }
  const float tgt_total = red[0];
  __syncthreads();
  red[t] = corr;
  __syncthreads();
  for (int s = 64; s > 0; s >>= 1) {
    if (t < s) red[t] += red[t + s];
    __syncthreads();
  }
  const float corr_total = red[0];
  const bool uniqueAll = (dupCount == 0);
  __syncthreads();

  if (uniqueAll && t < M_) {
    const unsigned v = asg[t];
    int rank = 0;
    for (int m = 0; m < M_; ++m) rank += (asg[m] < v) ? 1 : 0;
    srt[rank] = v;
  }
  __syncthreads();

  float gl = 0.f;
  if (t < M_) {
    const unsigned q = uniqueAll ? srt[t] : asg[t];
    float4 r = reinterpret_cast<const float4*>(pred_reg)[(size_t)b * N_ + q];
    float2 a = reinterpret_cast<const float2*>(anchors)[q];
    float s = strides[q];
    float cx = a.x + r.x * s, cy = a.y + r.y * s;
    float hx = (expf(r.z) * s) * 0.5f, hy = (expf(r.w) * s) * 0.5f;
    float px0 = cx - hx, py0 = cy - hy, px1 = cx + hx, py1 = cy + hy;
    float4 g = reinterpret_cast<const float4*>(gt_boxes)[b * M_ + t];
    float ap = (px1 - px0) * (py1 - py0);
    float ag = (g.z - g.x) * (g.w - g.y);
    float ltx = fmaxf(px0, g.x), lty = fmaxf(py0, g.y);
    float rbx = fminf(px1, g.z), rby = fminf(py1, g.w);
    float wix = fmaxf(rbx - ltx, 0.f), wiy = fmaxf(rby - lty, 0.f);
    float inter = wix * wiy;
    float uni = ap + ag - inter;
    float iou = inter / (uni + EPSF);
    float lcx = fminf(px0, g.x), lcy = fminf(py0, g.y);
    float rcx = fmaxf(px1, g.z), rcy = fmaxf(py1, g.w);
    float wcx = fmaxf(rcx - lcx, 0.f), wcy = fmaxf(rcy - lcy, 0.f);
    float ac = wcx * wcy;
    float giou = iou - (ac - uni) / (ac + EPSF);
    gl = 1.f - giou;
  }
  __syncthreads();
  red[t] = gl;
  __syncthreads();
  for (int s = 64; s > 0; s >>= 1) {
    if (t < s) red[t] += red[t + s];
    __syncthreads();
  }
  if (t == 0) {
    lb[b] = red[0] / (float)M_;
    float bce = (float)((sp_sum[b] - (double)tgt_total) / (double)(N_ * C_));
    float swm = (float)((swb_sum[b] + (double)corr_total) / (double)N_);
    lc[b] = bce * swm;
  }
}

// ---------------- scalar combine ----------------
__global__ void __launch_bounds__(64)
k_total(const float* __restrict__ lc, const float* __restrict__ lb,
        float* __restrict__ out) {
  if (threadIdx.x == 0 && blockIdx.x == 0) {
    float sc = 0.f, sb = 0.f;
    for (int b = 0; b < B_; ++b) { sc += lc[b]; sb += lb[b]; }
    out[0] = sc / 8.0f + 2.0f * (sb / 8.0f);
  }
}

// ---------------- launch ----------------
extern "C" void kernel_launch(void* const* d_in, const int* in_sizes, int n_in,
                              void* d_out, int out_size, void* d_ws, size_t ws_size,
                              hipStream_t stream) {
  (void)in_sizes; (void)n_in; (void)out_size; (void)ws_size;
  const float* pred_cls  = (const float*)d_in[0];
  const float* pred_reg  = (const float*)d_in[1];
  const float* anchors   = (const float*)d_in[2];
  const float* strides   = (const float*)d_in[3];
  const float* gt_boxes  = (const float*)d_in[4];
  const int*   gt_labels = (const int*)d_in[5];
  float* out = (float*)d_out;

  char* ws = (char*)d_ws;
  double* sp_sum  = (double*)(ws);                       // 8 doubles
  double* swb_sum = (double*)(ws + 64);                  // 8 doubles
  unsigned long long* amin = (unsigned long long*)(ws + 128);  // 800 u64
  float* lc = (float*)(ws + 128 + 6400);                 // 8 floats
  float* lb = (float*)(ws + 128 + 6400 + 32);            // 8 floats

  hipMemsetAsync(ws, 0, 128, stream);            // zero accumulators
  hipMemsetAsync(ws + 128, 0xFF, 6400, stream);  // amin = +inf pack

  k_passA<<<dim3(N_ / 1024, B_), dim3(256), 0, stream>>>(pred_cls, anchors, gt_boxes,
                                                         sp_sum, swb_sum);
  k_argmin<<<dim3(SEG_, B_ * M_), dim3(256), 0, stream>>>(anchors, gt_boxes, amin);
  k_final_img<<<dim3(B_), dim3(128), 0, stream>>>(pred_cls, pred_reg, anchors, strides,
                                                  gt_boxes, gt_labels, amin, sp_sum,
                                                  swb_sum, lc, lb);
  k_total<<<dim3(1), dim3(64), 0, stream>>>(lc, lb, out);
}

// Round 7
// 258.267 us; speedup vs baseline: 4.2837x; 1.1716x over previous
//
#include <hip/hip_runtime.h>

#define B_ 8
#define N_ 262144
#define M_ 100
#define C_ 7
#define EPSF 1e-7f
#define AB_ 2048                 // anchors per k_main block
#define CH_ (N_ / AB_)           // 128 chunks
#define APT_ 8                   // anchors per thread (AB_/256)
// fallback path (R6-proven) params
#define SEG_ 4
#define SEGN_ (N_ / SEG_)

__device__ __forceinline__ float softplus0(float x) {
  // jnp.logaddexp(0, x) = max(x,0) + log1p(exp(-|x|))
  return fmaxf(x, 0.0f) + log1pf(expf(-fabsf(x)));
}

__device__ __forceinline__ unsigned long long u64min(unsigned long long a,
                                                     unsigned long long b) {
  return b < a ? b : a;
}

// ---------------- k_main: softplus + neg-weight + per-chunk argmin partials ----------------
// grid (CH_, B), 256 threads. d2 computed ONCE per (gt, anchor) pair and used
// for both the per-anchor min (neg mask) and the per-GT argmin (u64-packed
// wave butterfly -> LDS -> one plain store per (b,m,chunk); NO contended atomics).
__global__ void __launch_bounds__(256)
k_main(const float* __restrict__ pred_cls,
       const float* __restrict__ anchors,
       const float* __restrict__ gt_boxes,
       double* __restrict__ sp_sum,
       double* __restrict__ swb_sum,
       unsigned long long* __restrict__ part) {
  const int b = blockIdx.y;
  const int c = blockIdx.x;   // anchor chunk (AB_ anchors)
  const int t = threadIdx.x;  // 256

  __shared__ float4 gt4[M_];                 // (gx, gy, gx^2+gy^2, -)
  __shared__ float red[256];
  __shared__ unsigned long long wb[M_][4];   // per-wave best per m

  if (t < M_) {
    float4 g = reinterpret_cast<const float4*>(gt_boxes)[b * M_ + t];
    float gx = __fmul_rn(__fadd_rn(g.x, g.z), 0.5f);
    float gy = __fmul_rn(__fadd_rn(g.y, g.w), 0.5f);
    gt4[t] = make_float4(gx, gy, __fadd_rn(__fmul_rn(gx, gx), __fmul_rn(gy, gy)), 0.f);
  }

  // ---- phase 1: softplus over this block's slice (AB_*C_ = 14336 floats =
  // 3584 float4 = 14/thread), fully retired before anchor state goes live.
  const float4* pc = reinterpret_cast<const float4*>(
      pred_cls + (size_t)b * (size_t)(N_ * C_) + (size_t)c * (AB_ * C_));
  float acc_sp = 0.f;
  for (int k = 0; k < 14; ++k) {
    float4 v = pc[t + k * 256];
    acc_sp += softplus0(v.x) + softplus0(v.y) + softplus0(v.z) + softplus0(v.w);
  }
  red[t] = acc_sp;
  __syncthreads();
  for (int s = 128; s > 0; s >>= 1) {
    if (t < s) red[t] += red[t + s];
    __syncthreads();
  }
  if (t == 0) atomicAdd(&sp_sum[b], (double)red[0]);

  // ---- phase 2: 8 anchors/thread; m-loop does d2 once per pair.
  const int n0 = c * AB_;
  float ax[APT_], ay[APT_], t2[APT_], mind[APT_];
#pragma unroll
  for (int k = 0; k < APT_; ++k) {
    float2 a = reinterpret_cast<const float2*>(anchors)[n0 + t + k * 256];
    ax[k] = a.x; ay[k] = a.y;
    t2[k] = __fadd_rn(__fmul_rn(a.x, a.x), __fmul_rn(a.y, a.y));
    mind[k] = __int_as_float(0x7f800000);
  }
  __syncthreads();  // gt4 ready

  const int wid  = t >> 6;
  const int lane = t & 63;
  for (int m = 0; m < M_; ++m) {
    const float4 g = gt4[m];
    float bd = __int_as_float(0x7f800000);
    int bk = 0;
#pragma unroll
    for (int k = 0; k < APT_; ++k) {
      float dot = __fmaf_rn(g.y, ay[k], __fmul_rn(g.x, ax[k]));
      float d2  = __fsub_rn(__fadd_rn(g.z, t2[k]), __fadd_rn(dot, dot));
      d2 = fmaxf(d2, 0.0f);                   // ref: sqrt(clip(d2,0))
      mind[k] = fminf(mind[k], d2);
      if (d2 < bd) { bd = d2; bk = k; }       // k asc == n asc -> lowest n
    }
    unsigned bn = (unsigned)(n0 + t + (bk << 8));
    unsigned long long pk =
        ((unsigned long long)__float_as_uint(bd) << 32) | (unsigned long long)bn;
#pragma unroll
    for (int s = 1; s < 64; s <<= 1) {
      unsigned long long o = __shfl_xor((unsigned long long)pk, s, 64);
      pk = u64min(pk, o);
    }
    if (lane == 0) wb[m][wid] = pk;
  }
  __syncthreads();

  // neg-weight partial sum
  float accw = 0.f;
#pragma unroll
  for (int k = 0; k < APT_; ++k) accw += (sqrtf(mind[k]) > 3.0f) ? 1.0f : 0.1f;
  red[t] = accw;
  __syncthreads();
  for (int s = 128; s > 0; s >>= 1) {
    if (t < s) red[t] += red[t + s];
    __syncthreads();
  }
  if (t == 0) atomicAdd(&swb_sum[b], (double)red[0]);

  // one plain store per (b, m, chunk)
  if (t < M_) {
    unsigned long long v = u64min(u64min(wb[t][0], wb[t][1]),
                                  u64min(wb[t][2], wb[t][3]));
    part[((size_t)(b * M_ + t)) * CH_ + c] = v;
  }
}

// ---------------- stage 2: reduce chunk partials -> amin ----------------
// grid (B*M), one wave. Coalesced u64 reads + butterfly; plain store.
__global__ void __launch_bounds__(64)
k_amin2(const unsigned long long* __restrict__ part,
        unsigned long long* __restrict__ amin) {
  const int bm = blockIdx.x;
  const int t  = threadIdx.x;  // 64
  const unsigned long long* p = part + (size_t)bm * CH_;
  unsigned long long v = u64min(p[t], p[t + 64]);
#pragma unroll
  for (int s = 1; s < 64; s <<= 1)
    v = u64min(v, __shfl_xor((unsigned long long)v, s, 64));
  if (t == 0) amin[bm] = v;
}

// ---------------- fallback (R6-proven) kernels, used if ws_size is small ----------------
__global__ void __launch_bounds__(256)
k_passA(const float* __restrict__ pred_cls,
        const float* __restrict__ anchors,
        const float* __restrict__ gt_boxes,
        double* __restrict__ sp_sum,
        double* __restrict__ swb_sum) {
  const int b = blockIdx.y;
  const int c = blockIdx.x;
  const int t = threadIdx.x;
  __shared__ float4 gt4[M_];
  __shared__ float red[256];
  if (t < M_) {
    float4 g = reinterpret_cast<const float4*>(gt_boxes)[b * M_ + t];
    float gx = __fmul_rn(__fadd_rn(g.x, g.z), 0.5f);
    float gy = __fmul_rn(__fadd_rn(g.y, g.w), 0.5f);
    gt4[t] = make_float4(gx, gy, __fadd_rn(__fmul_rn(gx, gx), __fmul_rn(gy, gy)), 0.f);
  }
  const float4* pc = reinterpret_cast<const float4*>(
      pred_cls + (size_t)b * (size_t)(N_ * C_) + (size_t)c * (1024 * C_));
  float acc_sp = 0.f;
#pragma unroll
  for (int k = 0; k < 7; ++k) {
    float4 v = pc[t + k * 256];
    acc_sp += softplus0(v.x) + softplus0(v.y) + softplus0(v.z) + softplus0(v.w);
  }
  red[t] = acc_sp;
  __syncthreads();
  for (int s = 128; s > 0; s >>= 1) {
    if (t < s) red[t] += red[t + s];
    __syncthreads();
  }
  if (t == 0) atomicAdd(&sp_sum[b], (double)red[0]);
  const int n0 = c * 1024;
  float ax[4], ay[4], t2[4], mind[4];
#pragma unroll
  for (int k = 0; k < 4; ++k) {
    float2 a = reinterpret_cast<const float2*>(anchors)[n0 + t + k * 256];
    ax[k] = a.x; ay[k] = a.y;
    t2[k] = __fadd_rn(__fmul_rn(a.x, a.x), __fmul_rn(a.y, a.y));
    mind[k] = __int_as_float(0x7f800000);
  }
#pragma unroll 2
  for (int m = 0; m < M_; ++m) {
    const float4 g = gt4[m];
#pragma unroll
    for (int k = 0; k < 4; ++k) {
      float dot = __fmaf_rn(g.y, ay[k], __fmul_rn(g.x, ax[k]));
      float d2  = __fsub_rn(__fadd_rn(g.z, t2[k]), __fadd_rn(dot, dot));
      mind[k] = fminf(mind[k], fmaxf(d2, 0.0f));
    }
  }
  float accw = 0.f;
#pragma unroll
  for (int k = 0; k < 4; ++k) accw += (sqrtf(mind[k]) > 3.0f) ? 1.0f : 0.1f;
  __syncthreads();
  red[t] = accw;
  __syncthreads();
  for (int s = 128; s > 0; s >>= 1) {
    if (t < s) red[t] += red[t + s];
    __syncthreads();
  }
  if (t == 0) atomicAdd(&swb_sum[b], (double)red[0]);
}

__global__ void __launch_bounds__(256)
k_argmin(const float* __restrict__ anchors,
         const float* __restrict__ gt_boxes,
         unsigned long long* __restrict__ amin) {
  const int bm  = blockIdx.y;
  const int seg = blockIdx.x;
  const float4 g = reinterpret_cast<const float4*>(gt_boxes)[bm];
  const float gx = __fmul_rn(__fadd_rn(g.x, g.z), 0.5f);
  const float gy = __fmul_rn(__fadd_rn(g.y, g.w), 0.5f);
  const float t1 = __fadd_rn(__fmul_rn(gx, gx), __fmul_rn(gy, gy));
  const float2* an = reinterpret_cast<const float2*>(anchors);
  float best = __int_as_float(0x7f800000);
  unsigned bestn = 0;
  const int n0 = seg * SEGN_;
#pragma unroll 4
  for (int n = n0 + threadIdx.x; n < n0 + SEGN_; n += 256) {
    float2 a = an[n];
    float t2  = __fadd_rn(__fmul_rn(a.x, a.x), __fmul_rn(a.y, a.y));
    float dot = __fmaf_rn(gy, a.y, __fmul_rn(gx, a.x));
    float d2  = __fsub_rn(__fadd_rn(t1, t2), __fadd_rn(dot, dot));
    d2 = fmaxf(d2, 0.0f);
    if (d2 < best) { best = d2; bestn = (unsigned)n; }
  }
  unsigned long long pk =
      ((unsigned long long)__float_as_uint(best) << 32) | (unsigned long long)bestn;
  __shared__ unsigned long long red[256];
  const int t = threadIdx.x;
  red[t] = pk;
  __syncthreads();
  for (int s = 128; s > 0; s >>= 1) {
    if (t < s) {
      unsigned long long o = red[t + s];
      if (o < red[t]) red[t] = o;
    }
    __syncthreads();
  }
  if (t == 0) atomicMin(&amin[bm], red[0]);
}

// ---------------- per-image finalize ----------------
__global__ void __launch_bounds__(128)
k_final_img(const float* __restrict__ pred_cls,
            const float* __restrict__ pred_reg,
            const float* __restrict__ anchors,
            const float* __restrict__ strides,
            const float* __restrict__ gt_boxes,
            const int* __restrict__ gt_labels,
            const unsigned long long* __restrict__ amin,
            const double* __restrict__ sp_sum,
            const double* __restrict__ swb_sum,
            float* __restrict__ lc, float* __restrict__ lb) {
  const int b = blockIdx.x;
  const int t = threadIdx.x;  // 128
  __shared__ unsigned asg[M_];
  __shared__ int cid[M_];
  __shared__ unsigned srt[M_];
  __shared__ float4 gt4[M_];
  __shared__ float red[128];
  __shared__ int dupCount;
  if (t == 0) dupCount = 0;
  if (t < M_) {
    asg[t] = (unsigned)(amin[b * M_ + t] & 0xffffffffULL);
    int c = gt_labels[b * M_ + t] - 1;
    c = c < 0 ? 0 : (c > C_ - 1 ? C_ - 1 : c);
    cid[t] = c;
    float4 g = reinterpret_cast<const float4*>(gt_boxes)[b * M_ + t];
    float gx = __fmul_rn(__fadd_rn(g.x, g.z), 0.5f);
    float gy = __fmul_rn(__fadd_rn(g.y, g.w), 0.5f);
    gt4[t] = make_float4(gx, gy, __fadd_rn(__fmul_rn(gx, gx), __fmul_rn(gy, gy)), 0.f);
  }
  __syncthreads();

  float tg = 0.f, corr = 0.f;
  if (t < M_) {
    bool dupPair = false, dupIdx = false;
    for (int m = 0; m < t; ++m) {
      if (asg[m] == asg[t]) {
        dupIdx = true;
        if (cid[m] == cid[t]) dupPair = true;
      }
    }
    if (!dupPair) tg = pred_cls[((size_t)b * N_ + asg[t]) * C_ + cid[t]];
    if (dupIdx) atomicAdd(&dupCount, 1);
    if (!dupIdx) {
      float2 a = reinterpret_cast<const float2*>(anchors)[asg[t]];
      float t2 = __fadd_rn(__fmul_rn(a.x, a.x), __fmul_rn(a.y, a.y));
      float mind = __int_as_float(0x7f800000);
      for (int m = 0; m < M_; ++m) {
        float4 g = gt4[m];
        float dot = __fmaf_rn(g.y, a.y, __fmul_rn(g.x, a.x));
        float d2  = __fsub_rn(__fadd_rn(g.z, t2), __fadd_rn(dot, dot));
        mind = fminf(mind, fmaxf(d2, 0.0f));
      }
      corr = (sqrtf(mind) > 3.0f) ? 1.0f : 0.1f;
    }
  }
  red[t] = tg;
  __syncthreads();
  for (int s = 64; s > 0; s >>= 1) {
    if (t < s) red[t] += red[t + s];
    __syncthreads();
  }
  const float tgt_total = red[0];
  __syncthreads();
  red[t] = corr;
  __syncthreads();
  for (int s = 64; s > 0; s >>= 1) {
    if (t < s) red[t] += red[t + s];
    __syncthreads();
  }
  const float corr_total = red[0];
  const bool uniqueAll = (dupCount == 0);
  __syncthreads();

  if (uniqueAll && t < M_) {
    const unsigned v = asg[t];
    int rank = 0;
    for (int m = 0; m < M_; ++m) rank += (asg[m] < v) ? 1 : 0;
    srt[rank] = v;
  }
  __syncthreads();

  float gl = 0.f;
  if (t < M_) {
    const unsigned q = uniqueAll ? srt[t] : asg[t];
    float4 r = reinterpret_cast<const float4*>(pred_reg)[(size_t)b * N_ + q];
    float2 a = reinterpret_cast<const float2*>(anchors)[q];
    float s = strides[q];
    float cx = a.x + r.x * s, cy = a.y + r.y * s;
    float hx = (expf(r.z) * s) * 0.5f, hy = (expf(r.w) * s) * 0.5f;
    float px0 = cx - hx, py0 = cy - hy, px1 = cx + hx, py1 = cy + hy;
    float4 g = reinterpret_cast<const float4*>(gt_boxes)[b * M_ + t];
    float ap = (px1 - px0) * (py1 - py0);
    float ag = (g.z - g.x) * (g.w - g.y);
    float ltx = fmaxf(px0, g.x), lty = fmaxf(py0, g.y);
    float rbx = fminf(px1, g.z), rby = fminf(py1, g.w);
    float wix = fmaxf(rbx - ltx, 0.f), wiy = fmaxf(rby - lty, 0.f);
    float inter = wix * wiy;
    float uni = ap + ag - inter;
    float iou = inter / (uni + EPSF);
    float lcx = fminf(px0, g.x), lcy = fminf(py0, g.y);
    float rcx = fmaxf(px1, g.z), rcy = fmaxf(py1, g.w);
    float wcx = fmaxf(rcx - lcx, 0.f), wcy = fmaxf(rcy - lcy, 0.f);
    float ac = wcx * wcy;
    float giou = iou - (ac - uni) / (ac + EPSF);
    gl = 1.f - giou;
  }
  __syncthreads();
  red[t] = gl;
  __syncthreads();
  for (int s = 64; s > 0; s >>= 1) {
    if (t < s) red[t] += red[t + s];
    __syncthreads();
  }
  if (t == 0) {
    lb[b] = red[0] / (float)M_;
    float bce = (float)((sp_sum[b] - (double)tgt_total) / (double)(N_ * C_));
    float swm = (float)((swb_sum[b] + (double)corr_total) / (double)N_);
    lc[b] = bce * swm;
  }
}

// ---------------- scalar combine ----------------
__global__ void __launch_bounds__(64)
k_total(const float* __restrict__ lc, const float* __restrict__ lb,
        float* __restrict__ out) {
  if (threadIdx.x == 0 && blockIdx.x == 0) {
    float sc = 0.f, sb = 0.f;
    for (int b = 0; b < B_; ++b) { sc += lc[b]; sb += lb[b]; }
    out[0] = sc / 8.0f + 2.0f * (sb / 8.0f);
  }
}

// ---------------- launch ----------------
extern "C" void kernel_launch(void* const* d_in, const int* in_sizes, int n_in,
                              void* d_out, int out_size, void* d_ws, size_t ws_size,
                              hipStream_t stream) {
  (void)in_sizes; (void)n_in; (void)out_size;
  const float* pred_cls  = (const float*)d_in[0];
  const float* pred_reg  = (const float*)d_in[1];
  const float* anchors   = (const float*)d_in[2];
  const float* strides   = (const float*)d_in[3];
  const float* gt_boxes  = (const float*)d_in[4];
  const int*   gt_labels = (const int*)d_in[5];
  float* out = (float*)d_out;

  char* ws = (char*)d_ws;
  double* sp_sum  = (double*)(ws);                       // 8 doubles
  double* swb_sum = (double*)(ws + 64);                  // 8 doubles

  const size_t part_off = 128;
  const size_t part_bytes = (size_t)B_ * M_ * CH_ * 8;   // 819200
  const size_t amin_off = part_off + part_bytes;
  const size_t need = amin_off + 6400 + 64 + 64;

  if (ws_size >= need) {
    unsigned long long* part = (unsigned long long*)(ws + part_off);
    unsigned long long* amin = (unsigned long long*)(ws + amin_off);
    float* lc = (float*)(ws + amin_off + 6400);
    float* lb = (float*)(ws + amin_off + 6400 + 64);

    hipMemsetAsync(ws, 0, 128, stream);  // zero f64 accumulators
    k_main<<<dim3(CH_, B_), dim3(256), 0, stream>>>(pred_cls, anchors, gt_boxes,
                                                    sp_sum, swb_sum, part);
    k_amin2<<<dim3(B_ * M_), dim3(64), 0, stream>>>(part, amin);
    k_final_img<<<dim3(B_), dim3(128), 0, stream>>>(pred_cls, pred_reg, anchors,
                                                    strides, gt_boxes, gt_labels,
                                                    amin, sp_sum, swb_sum, lc, lb);
    k_total<<<dim3(1), dim3(64), 0, stream>>>(lc, lb, out);
  } else {
    // R6-proven fallback (needs ~7 KB)
    unsigned long long* amin = (unsigned long long*)(ws + 128);
    float* lc = (float*)(ws + 128 + 6400);
    float* lb = (float*)(ws + 128 + 6400 + 32);
    hipMemsetAsync(ws, 0, 128, stream);
    hipMemsetAsync(ws + 128, 0xFF, 6400, stream);
    k_passA<<<dim3(N_ / 1024, B_), dim3(256), 0, stream>>>(pred_cls, anchors, gt_boxes,
                                                           sp_sum, swb_sum);
    k_argmin<<<dim3(SEG_, B_ * M_), dim3(256), 0, stream>>>(anchors, gt_boxes, amin);
    k_final_img<<<dim3(B_), dim3(128), 0, stream>>>(pred_cls, pred_reg, anchors,
                                                    strides, gt_boxes, gt_labels,
                                                    amin, sp_sum, swb_sum, lc, lb);
    k_total<<<dim3(1), dim3(64), 0, stream>>>(lc, lb, out);
  }
}

// Round 8
// 249.483 us; speedup vs baseline: 4.4345x; 1.0352x over previous
//
#include <hip/hip_runtime.h>

#define B_ 8
#define N_ 262144
#define M_ 100
#define C_ 7
#define EPSF 1e-7f
#define AB_ 2048                 // anchors per k_main block
#define CH_ (N_ / AB_)           // 128 chunks
#define APT_ 8                   // anchors per thread (AB_/256)
// fallback path (R6-proven) params
#define SEG_ 4
#define SEGN_ (N_ / SEG_)

typedef unsigned long long ull;

__device__ __forceinline__ float softplus0(float x) {
  // jnp.logaddexp(0, x) = max(x,0) + log1p(exp(-|x|))
  return fmaxf(x, 0.0f) + log1pf(expf(-fabsf(x)));
}

__device__ __forceinline__ ull u64min(ull a, ull b) { return b < a ? b : a; }

// ---------------- k_main: softplus + neg-weight + per-chunk argmin partials ----------------
// grid (CH_, B), 256 threads. d2 computed ONCE per (gt, anchor) pair; per-GT
// argmin via packed-u64 min chain + raw ds_bpermute butterfly (hoisted lane
// indices — R7 post-mortem: __shfl_xor's per-call index math was ~3x the
// butterfly's real cost). No contended atomics anywhere.
__global__ void __launch_bounds__(256)
k_main(const float* __restrict__ pred_cls,
       const float* __restrict__ anchors,
       const float* __restrict__ gt_boxes,
       double* __restrict__ sp_sum,
       double* __restrict__ swb_sum,
       ull* __restrict__ part) {
  const int b = blockIdx.y;
  const int c = blockIdx.x;   // anchor chunk (AB_ anchors)
  const int t = threadIdx.x;  // 256

  __shared__ float4 gt4[M_];   // (gx, gy, gx^2+gy^2, -)
  __shared__ float red[256];
  __shared__ ull wb[M_][4];    // per-wave best per m

  if (t < M_) {
    float4 g = reinterpret_cast<const float4*>(gt_boxes)[b * M_ + t];
    float gx = __fmul_rn(__fadd_rn(g.x, g.z), 0.5f);
    float gy = __fmul_rn(__fadd_rn(g.y, g.w), 0.5f);
    gt4[t] = make_float4(gx, gy, __fadd_rn(__fmul_rn(gx, gx), __fmul_rn(gy, gy)), 0.f);
  }

  // ---- phase 1: softplus over this block's slice (AB_*C_ = 14336 floats),
  // fully retired before anchor state goes live (R5 lesson: no spill).
  const float4* pc = reinterpret_cast<const float4*>(
      pred_cls + (size_t)b * (size_t)(N_ * C_) + (size_t)c * (AB_ * C_));
  float acc_sp = 0.f;
  for (int k = 0; k < 14; ++k) {
    float4 v = pc[t + k * 256];
    acc_sp += softplus0(v.x) + softplus0(v.y) + softplus0(v.z) + softplus0(v.w);
  }
  red[t] = acc_sp;
  __syncthreads();
  for (int s = 128; s > 0; s >>= 1) {
    if (t < s) red[t] += red[t + s];
    __syncthreads();
  }
  if (t == 0) atomicAdd(&sp_sum[b], (double)red[0]);

  // ---- phase 2: 8 anchors/thread; m-loop does d2 once per pair.
  const int n0 = c * AB_;
  float ax[APT_], ay[APT_], t2[APT_], mind[APT_];
  unsigned nn[APT_];
#pragma unroll
  for (int k = 0; k < APT_; ++k) {
    float2 a = reinterpret_cast<const float2*>(anchors)[n0 + t + k * 256];
    ax[k] = a.x; ay[k] = a.y;
    t2[k] = __fadd_rn(__fmul_rn(a.x, a.x), __fmul_rn(a.y, a.y));
    mind[k] = __int_as_float(0x7f800000);
    nn[k] = (unsigned)(n0 + t + (k << 8));   // loop-invariant over m
  }
  const int wid  = t >> 6;
  const int lane = t & 63;
  int bidx[6];
#pragma unroll
  for (int i = 0; i < 6; ++i) bidx[i] = ((lane ^ (1 << i)) << 2);  // byte idx, hoisted
  __syncthreads();  // gt4 ready

#pragma unroll 2
  for (int m = 0; m < M_; ++m) {
    const float4 g = gt4[m];
    ull pk = 0xffffffffffffffffULL;
#pragma unroll
    for (int k = 0; k < APT_; ++k) {
      float dot = __fmaf_rn(g.y, ay[k], __fmul_rn(g.x, ax[k]));
      float d2  = __fsub_rn(__fadd_rn(g.z, t2[k]), __fadd_rn(dot, dot));
      d2 = fmaxf(d2, 0.0f);                   // ref: sqrt(clip(d2,0))
      mind[k] = fminf(mind[k], d2);
      ull cand = ((ull)__float_as_uint(d2) << 32) | (ull)nn[k];
      pk = u64min(pk, cand);                  // exact (d2, lowest-n) order
    }
    // 6-step wave64 butterfly: 2 bpermute + u64 min per step.
#pragma unroll
    for (int i = 0; i < 6; ++i) {
      int lo = __builtin_amdgcn_ds_bpermute(bidx[i], (int)(unsigned)(pk & 0xffffffffULL));
      int hi = __builtin_amdgcn_ds_bpermute(bidx[i], (int)(unsigned)(pk >> 32));
      ull o = ((ull)(unsigned)hi << 32) | (ull)(unsigned)lo;
      pk = u64min(pk, o);
    }
    if (lane == 0) wb[m][wid] = pk;
  }
  __syncthreads();

  // neg-weight partial sum
  float accw = 0.f;
#pragma unroll
  for (int k = 0; k < APT_; ++k) accw += (sqrtf(mind[k]) > 3.0f) ? 1.0f : 0.1f;
  red[t] = accw;
  __syncthreads();
  for (int s = 128; s > 0; s >>= 1) {
    if (t < s) red[t] += red[t + s];
    __syncthreads();
  }
  if (t == 0) atomicAdd(&swb_sum[b], (double)red[0]);

  // one plain store per (b, m, chunk)
  if (t < M_) {
    ull v = u64min(u64min(wb[t][0], wb[t][1]), u64min(wb[t][2], wb[t][3]));
    part[((size_t)(b * M_ + t)) * CH_ + c] = v;
  }
}

// ---------------- finalize (main path): chunk-partial reduce + per-image losses ----------------
__global__ void __launch_bounds__(128)
k_final2(const float* __restrict__ pred_cls,
         const float* __restrict__ pred_reg,
         const float* __restrict__ anchors,
         const float* __restrict__ strides,
         const float* __restrict__ gt_boxes,
         const int* __restrict__ gt_labels,
         const ull* __restrict__ part,
         const double* __restrict__ sp_sum,
         const double* __restrict__ swb_sum,
         float* __restrict__ lc, float* __restrict__ lb) {
  const int b = blockIdx.x;
  const int t = threadIdx.x;  // 128
  __shared__ unsigned asg[M_];
  __shared__ int cid[M_];
  __shared__ unsigned srt[M_];
  __shared__ float4 gt4[M_];
  __shared__ float red[128];
  __shared__ int dupCount;
  if (t == 0) dupCount = 0;
  if (t < M_) {
    // reduce this m's 128 chunk partials (4 independent chains)
    const ull* p = part + ((size_t)(b * M_ + t)) * CH_;
    ull v0 = 0xffffffffffffffffULL, v1 = v0, v2 = v0, v3 = v0;
    for (int c = 0; c < CH_; c += 4) {
      v0 = u64min(v0, p[c]);
      v1 = u64min(v1, p[c + 1]);
      v2 = u64min(v2, p[c + 2]);
      v3 = u64min(v3, p[c + 3]);
    }
    asg[t] = (unsigned)(u64min(u64min(v0, v1), u64min(v2, v3)) & 0xffffffffULL);
    int cc = gt_labels[b * M_ + t] - 1;
    cc = cc < 0 ? 0 : (cc > C_ - 1 ? C_ - 1 : cc);
    cid[t] = cc;
    float4 g = reinterpret_cast<const float4*>(gt_boxes)[b * M_ + t];
    float gx = __fmul_rn(__fadd_rn(g.x, g.z), 0.5f);
    float gy = __fmul_rn(__fadd_rn(g.y, g.w), 0.5f);
    gt4[t] = make_float4(gx, gy, __fadd_rn(__fmul_rn(gx, gx), __fmul_rn(gy, gy)), 0.f);
  }
  __syncthreads();

  // tgt sum with (anchor,cls)-pair dedup; anchor-dup detection for uniqueness;
  // pos-correction: for each DISTINCT assigned anchor add its neg-weight.
  float tg = 0.f, corr = 0.f;
  if (t < M_) {
    bool dupPair = false, dupIdx = false;
    for (int m = 0; m < t; ++m) {
      if (asg[m] == asg[t]) {
        dupIdx = true;
        if (cid[m] == cid[t]) dupPair = true;
      }
    }
    if (!dupPair) tg = pred_cls[((size_t)b * N_ + asg[t]) * C_ + cid[t]];
    if (dupIdx) atomicAdd(&dupCount, 1);
    if (!dupIdx) {
      float2 a = reinterpret_cast<const float2*>(anchors)[asg[t]];
      float t2 = __fadd_rn(__fmul_rn(a.x, a.x), __fmul_rn(a.y, a.y));
      float mind = __int_as_float(0x7f800000);
      for (int m = 0; m < M_; ++m) {
        float4 g = gt4[m];
        float dot = __fmaf_rn(g.y, a.y, __fmul_rn(g.x, a.x));
        float d2  = __fsub_rn(__fadd_rn(g.z, t2), __fadd_rn(dot, dot));
        mind = fminf(mind, fmaxf(d2, 0.0f));
      }
      corr = (sqrtf(mind) > 3.0f) ? 1.0f : 0.1f;
    }
  }
  red[t] = tg;
  __syncthreads();
  for (int s = 64; s > 0; s >>= 1) {
    if (t < s) red[t] += red[t + s];
    __syncthreads();
  }
  const float tgt_total = red[0];
  __syncthreads();
  red[t] = corr;
  __syncthreads();
  for (int s = 64; s > 0; s >>= 1) {
    if (t < s) red[t] += red[t + s];
    __syncthreads();
  }
  const float corr_total = red[0];
  const bool uniqueAll = (dupCount == 0);
  __syncthreads();

  if (uniqueAll && t < M_) {
    const unsigned v = asg[t];
    int rank = 0;
    for (int m = 0; m < M_; ++m) rank += (asg[m] < v) ? 1 : 0;
    srt[rank] = v;
  }
  __syncthreads();

  float gl = 0.f;
  if (t < M_) {
    const unsigned q = uniqueAll ? srt[t] : asg[t];
    float4 r = reinterpret_cast<const float4*>(pred_reg)[(size_t)b * N_ + q];
    float2 a = reinterpret_cast<const float2*>(anchors)[q];
    float s = strides[q];
    float cx = a.x + r.x * s, cy = a.y + r.y * s;
    float hx = (expf(r.z) * s) * 0.5f, hy = (expf(r.w) * s) * 0.5f;
    float px0 = cx - hx, py0 = cy - hy, px1 = cx + hx, py1 = cy + hy;
    float4 g = reinterpret_cast<const float4*>(gt_boxes)[b * M_ + t];
    float ap = (px1 - px0) * (py1 - py0);
    float ag = (g.z - g.x) * (g.w - g.y);
    float ltx = fmaxf(px0, g.x), lty = fmaxf(py0, g.y);
    float rbx = fminf(px1, g.z), rby = fminf(py1, g.w);
    float wix = fmaxf(rbx - ltx, 0.f), wiy = fmaxf(rby - lty, 0.f);
    float inter = wix * wiy;
    float uni = ap + ag - inter;
    float iou = inter / (uni + EPSF);
    float lcx = fminf(px0, g.x), lcy = fminf(py0, g.y);
    float rcx = fmaxf(px1, g.z), rcy = fmaxf(py1, g.w);
    float wcx = fmaxf(rcx - lcx, 0.f), wcy = fmaxf(rcy - lcy, 0.f);
    float ac = wcx * wcy;
    float giou = iou - (ac - uni) / (ac + EPSF);
    gl = 1.f - giou;
  }
  __syncthreads();
  red[t] = gl;
  __syncthreads();
  for (int s = 64; s > 0; s >>= 1) {
    if (t < s) red[t] += red[t + s];
    __syncthreads();
  }
  if (t == 0) {
    lb[b] = red[0] / (float)M_;
    float bce = (float)((sp_sum[b] - (double)tgt_total) / (double)(N_ * C_));
    float swm = (float)((swb_sum[b] + (double)corr_total) / (double)N_);
    lc[b] = bce * swm;
  }
}

// ---------------- fallback (R6-proven) kernels, used if ws_size is small ----------------
__global__ void __launch_bounds__(256)
k_passA(const float* __restrict__ pred_cls,
        const float* __restrict__ anchors,
        const float* __restrict__ gt_boxes,
        double* __restrict__ sp_sum,
        double* __restrict__ swb_sum) {
  const int b = blockIdx.y;
  const int c = blockIdx.x;
  const int t = threadIdx.x;
  __shared__ float4 gt4[M_];
  __shared__ float red[256];
  if (t < M_) {
    float4 g = reinterpret_cast<const float4*>(gt_boxes)[b * M_ + t];
    float gx = __fmul_rn(__fadd_rn(g.x, g.z), 0.5f);
    float gy = __fmul_rn(__fadd_rn(g.y, g.w), 0.5f);
    gt4[t] = make_float4(gx, gy, __fadd_rn(__fmul_rn(gx, gx), __fmul_rn(gy, gy)), 0.f);
  }
  const float4* pc = reinterpret_cast<const float4*>(
      pred_cls + (size_t)b * (size_t)(N_ * C_) + (size_t)c * (1024 * C_));
  float acc_sp = 0.f;
#pragma unroll
  for (int k = 0; k < 7; ++k) {
    float4 v = pc[t + k * 256];
    acc_sp += softplus0(v.x) + softplus0(v.y) + softplus0(v.z) + softplus0(v.w);
  }
  red[t] = acc_sp;
  __syncthreads();
  for (int s = 128; s > 0; s >>= 1) {
    if (t < s) red[t] += red[t + s];
    __syncthreads();
  }
  if (t == 0) atomicAdd(&sp_sum[b], (double)red[0]);
  const int n0 = c * 1024;
  float ax[4], ay[4], t2[4], mind[4];
#pragma unroll
  for (int k = 0; k < 4; ++k) {
    float2 a = reinterpret_cast<const float2*>(anchors)[n0 + t + k * 256];
    ax[k] = a.x; ay[k] = a.y;
    t2[k] = __fadd_rn(__fmul_rn(a.x, a.x), __fmul_rn(a.y, a.y));
    mind[k] = __int_as_float(0x7f800000);
  }
#pragma unroll 2
  for (int m = 0; m < M_; ++m) {
    const float4 g = gt4[m];
#pragma unroll
    for (int k = 0; k < 4; ++k) {
      float dot = __fmaf_rn(g.y, ay[k], __fmul_rn(g.x, ax[k]));
      float d2  = __fsub_rn(__fadd_rn(g.z, t2[k]), __fadd_rn(dot, dot));
      mind[k] = fminf(mind[k], fmaxf(d2, 0.0f));
    }
  }
  float accw = 0.f;
#pragma unroll
  for (int k = 0; k < 4; ++k) accw += (sqrtf(mind[k]) > 3.0f) ? 1.0f : 0.1f;
  __syncthreads();
  red[t] = accw;
  __syncthreads();
  for (int s = 128; s > 0; s >>= 1) {
    if (t < s) red[t] += red[t + s];
    __syncthreads();
  }
  if (t == 0) atomicAdd(&swb_sum[b], (double)red[0]);
}

__global__ void __launch_bounds__(256)
k_argmin(const float* __restrict__ anchors,
         const float* __restrict__ gt_boxes,
         ull* __restrict__ amin) {
  const int bm  = blockIdx.y;
  const int seg = blockIdx.x;
  const float4 g = reinterpret_cast<const float4*>(gt_boxes)[bm];
  const float gx = __fmul_rn(__fadd_rn(g.x, g.z), 0.5f);
  const float gy = __fmul_rn(__fadd_rn(g.y, g.w), 0.5f);
  const float t1 = __fadd_rn(__fmul_rn(gx, gx), __fmul_rn(gy, gy));
  const float2* an = reinterpret_cast<const float2*>(anchors);
  float best = __int_as_float(0x7f800000);
  unsigned bestn = 0;
  const int n0 = seg * SEGN_;
#pragma unroll 4
  for (int n = n0 + threadIdx.x; n < n0 + SEGN_; n += 256) {
    float2 a = an[n];
    float t2  = __fadd_rn(__fmul_rn(a.x, a.x), __fmul_rn(a.y, a.y));
    float dot = __fmaf_rn(gy, a.y, __fmul_rn(gx, a.x));
    float d2  = __fsub_rn(__fadd_rn(t1, t2), __fadd_rn(dot, dot));
    d2 = fmaxf(d2, 0.0f);
    if (d2 < best) { best = d2; bestn = (unsigned)n; }
  }
  ull pk = ((ull)__float_as_uint(best) << 32) | (ull)bestn;
  __shared__ ull red[256];
  const int t = threadIdx.x;
  red[t] = pk;
  __syncthreads();
  for (int s = 128; s > 0; s >>= 1) {
    if (t < s) {
      ull o = red[t + s];
      if (o < red[t]) red[t] = o;
    }
    __syncthreads();
  }
  if (t == 0) atomicMin(&amin[bm], red[0]);
}

__global__ void __launch_bounds__(128)
k_final_img(const float* __restrict__ pred_cls,
            const float* __restrict__ pred_reg,
            const float* __restrict__ anchors,
            const float* __restrict__ strides,
            const float* __restrict__ gt_boxes,
            const int* __restrict__ gt_labels,
            const ull* __restrict__ amin,
            const double* __restrict__ sp_sum,
            const double* __restrict__ swb_sum,
            float* __restrict__ lc, float* __restrict__ lb) {
  const int b = blockIdx.x;
  const int t = threadIdx.x;  // 128
  __shared__ unsigned asg[M_];
  __shared__ int cid[M_];
  __shared__ unsigned srt[M_];
  __shared__ float4 gt4[M_];
  __shared__ float red[128];
  __shared__ int dupCount;
  if (t == 0) dupCount = 0;
  if (t < M_) {
    asg[t] = (unsigned)(amin[b * M_ + t] & 0xffffffffULL);
    int c = gt_labels[b * M_ + t] - 1;
    c = c < 0 ? 0 : (c > C_ - 1 ? C_ - 1 : c);
    cid[t] = c;
    float4 g = reinterpret_cast<const float4*>(gt_boxes)[b * M_ + t];
    float gx = __fmul_rn(__fadd_rn(g.x, g.z), 0.5f);
    float gy = __fmul_rn(__fadd_rn(g.y, g.w), 0.5f);
    gt4[t] = make_float4(gx, gy, __fadd_rn(__fmul_rn(gx, gx), __fmul_rn(gy, gy)), 0.f);
  }
  __syncthreads();

  float tg = 0.f, corr = 0.f;
  if (t < M_) {
    bool dupPair = false, dupIdx = false;
    for (int m = 0; m < t; ++m) {
      if (asg[m] == asg[t]) {
        dupIdx = true;
        if (cid[m] == cid[t]) dupPair = true;
      }
    }
    if (!dupPair) tg = pred_cls[((size_t)b * N_ + asg[t]) * C_ + cid[t]];
    if (dupIdx) atomicAdd(&dupCount, 1);
    if (!dupIdx) {
      float2 a = reinterpret_cast<const float2*>(anchors)[asg[t]];
      float t2 = __fadd_rn(__fmul_rn(a.x, a.x), __fmul_rn(a.y, a.y));
      float mind = __int_as_float(0x7f800000);
      for (int m = 0; m < M_; ++m) {
        float4 g = gt4[m];
        float dot = __fmaf_rn(g.y, a.y, __fmul_rn(g.x, a.x));
        float d2  = __fsub_rn(__fadd_rn(g.z, t2), __fadd_rn(dot, dot));
        mind = fminf(mind, fmaxf(d2, 0.0f));
      }
      corr = (sqrtf(mind) > 3.0f) ? 1.0f : 0.1f;
    }
  }
  red[t] = tg;
  __syncthreads();
  for (int s = 64; s > 0; s >>= 1) {
    if (t < s) red[t] += red[t + s];
    __syncthreads();
  }
  const float tgt_total = red[0];
  __syncthreads();
  red[t] = corr;
  __syncthreads();
  for (int s = 64; s > 0; s >>= 1) {
    if (t < s) red[t] += red[t + s];
    __syncthreads();
  }
  const float corr_total = red[0];
  const bool uniqueAll = (dupCount == 0);
  __syncthreads();

  if (uniqueAll && t < M_) {
    const unsigned v = asg[t];
    int rank = 0;
    for (int m = 0; m < M_; ++m) rank += (asg[m] < v) ? 1 : 0;
    srt[rank] = v;
  }
  __syncthreads();

  float gl = 0.f;
  if (t < M_) {
    const unsigned q = uniqueAll ? srt[t] : asg[t];
    float4 r = reinterpret_cast<const float4*>(pred_reg)[(size_t)b * N_ + q];
    float2 a = reinterpret_cast<const float2*>(anchors)[q];
    float s = strides[q];
    float cx = a.x + r.x * s, cy = a.y + r.y * s;
    float hx = (expf(r.z) * s) * 0.5f, hy = (expf(r.w) * s) * 0.5f;
    float px0 = cx - hx, py0 = cy - hy, px1 = cx + hx, py1 = cy + hy;
    float4 g = reinterpret_cast<const float4*>(gt_boxes)[b * M_ + t];
    float ap = (px1 - px0) * (py1 - py0);
    float ag = (g.z - g.x) * (g.w - g.y);
    float ltx = fmaxf(px0, g.x), lty = fmaxf(py0, g.y);
    float rbx = fminf(px1, g.z), rby = fminf(py1, g.w);
    float wix = fmaxf(rbx - ltx, 0.f), wiy = fmaxf(rby - lty, 0.f);
    float inter = wix * wiy;
    float uni = ap + ag - inter;
    float iou = inter / (uni + EPSF);
    float lcx = fminf(px0, g.x), lcy = fminf(py0, g.y);
    float rcx = fmaxf(px1, g.z), rcy = fmaxf(py1, g.w);
    float wcx = fmaxf(rcx - lcx, 0.f), wcy = fmaxf(rcy - lcy, 0.f);
    float ac = wcx * wcy;
    float giou = iou - (ac - uni) / (ac + EPSF);
    gl = 1.f - giou;
  }
  __syncthreads();
  red[t] = gl;
  __syncthreads();
  for (int s = 64; s > 0; s >>= 1) {
    if (t < s) red[t] += red[t + s];
    __syncthreads();
  }
  if (t == 0) {
    lb[b] = red[0] / (float)M_;
    float bce = (float)((sp_sum[b] - (double)tgt_total) / (double)(N_ * C_));
    float swm = (float)((swb_sum[b] + (double)corr_total) / (double)N_);
    lc[b] = bce * swm;
  }
}

// ---------------- scalar combine ----------------
__global__ void __launch_bounds__(64)
k_total(const float* __restrict__ lc, const float* __restrict__ lb,
        float* __restrict__ out) {
  if (threadIdx.x == 0 && blockIdx.x == 0) {
    float sc = 0.f, sb = 0.f;
    for (int b = 0; b < B_; ++b) { sc += lc[b]; sb += lb[b]; }
    out[0] = sc / 8.0f + 2.0f * (sb / 8.0f);
  }
}

// ---------------- launch ----------------
extern "C" void kernel_launch(void* const* d_in, const int* in_sizes, int n_in,
                              void* d_out, int out_size, void* d_ws, size_t ws_size,
                              hipStream_t stream) {
  (void)in_sizes; (void)n_in; (void)out_size;
  const float* pred_cls  = (const float*)d_in[0];
  const float* pred_reg  = (const float*)d_in[1];
  const float* anchors   = (const float*)d_in[2];
  const float* strides   = (const float*)d_in[3];
  const float* gt_boxes  = (const float*)d_in[4];
  const int*   gt_labels = (const int*)d_in[5];
  float* out = (float*)d_out;

  char* ws = (char*)d_ws;
  double* sp_sum  = (double*)(ws);                       // 8 doubles
  double* swb_sum = (double*)(ws + 64);                  // 8 doubles

  const size_t part_off = 128;
  const size_t part_bytes = (size_t)B_ * M_ * CH_ * 8;   // 819200
  const size_t tail_off = part_off + part_bytes;
  const size_t need = tail_off + 64 + 64;

  if (ws_size >= need) {
    ull* part = (ull*)(ws + part_off);
    float* lc = (float*)(ws + tail_off);
    float* lb = (float*)(ws + tail_off + 64);

    hipMemsetAsync(ws, 0, 128, stream);  // zero f64 accumulators
    k_main<<<dim3(CH_, B_), dim3(256), 0, stream>>>(pred_cls, anchors, gt_boxes,
                                                    sp_sum, swb_sum, part);
    k_final2<<<dim3(B_), dim3(128), 0, stream>>>(pred_cls, pred_reg, anchors,
                                                 strides, gt_boxes, gt_labels,
                                                 part, sp_sum, swb_sum, lc, lb);
    k_total<<<dim3(1), dim3(64), 0, stream>>>(lc, lb, out);
  } else {
    // R6-proven fallback (needs ~7 KB)
    ull* amin = (ull*)(ws + 128);
    float* lc = (float*)(ws + 128 + 6400);
    float* lb = (float*)(ws + 128 + 6400 + 32);
    hipMemsetAsync(ws, 0, 128, stream);
    hipMemsetAsync(ws + 128, 0xFF, 6400, stream);
    k_passA<<<dim3(N_ / 1024, B_), dim3(256), 0, stream>>>(pred_cls, anchors, gt_boxes,
                                                           sp_sum, swb_sum);
    k_argmin<<<dim3(SEG_, B_ * M_), dim3(256), 0, stream>>>(anchors, gt_boxes, amin);
    k_final_img<<<dim3(B_), dim3(128), 0, stream>>>(pred_cls, pred_reg, anchors,
                                                    strides, gt_boxes, gt_labels,
                                                    amin, sp_sum, swb_sum, lc, lb);
    k_total<<<dim3(1), dim3(64), 0, stream>>>(lc, lb, out);
  }
}